// Round 4
// baseline (324.170 us; speedup 1.0000x reference)
//
#include <hip/hip_runtime.h>

typedef unsigned short u16;
typedef unsigned int u32;
typedef __attribute__((ext_vector_type(8))) short bf16x8;
typedef __attribute__((ext_vector_type(4))) float f32x4;

#define NND 50000
#define NE 800000
#define NH 8
#define ND 32
#define NTY 5

__device__ inline u16 f2bf(float x){
  u32 u = __float_as_uint(x);
  return (u16)((u + 0x7FFFu + ((u >> 16) & 1u)) >> 16);
}

// ---------------- GEMM: feat[M,256] @ fc_w[256,256]^T -> feat_src bf16 [M,256]
__global__ __launch_bounds__(512, 4) void gemm_k(const float* __restrict__ A,
                                                 const float* __restrict__ W,
                                                 u16* __restrict__ C, int M){
  __shared__ float As[128 * 64];
  __shared__ u16  Ws[256 * 64];
  const int tid  = threadIdx.x;
  const int m0   = blockIdx.x * 128;
  const int lane = tid & 63, wid = tid >> 6;
  const int wm = (wid >> 2) * 64, wn = (wid & 3) * 64;
  const int ml = lane & 15, quad = lane >> 4;

  f32x4 acc[4][4] = {};

  const int ra = tid >> 2, ca = (tid & 3) * 4;
  int rag = m0 + ra; if (rag >= M) rag = M - 1;
  const float* aRow = A + (size_t)rag * 256;
  const int rw = tid >> 1, hw = tid & 1;
  const float* wRow = W + (size_t)rw * 256;

  for (int k0 = 0; k0 < 256; k0 += 64){
    #pragma unroll
    for (int q = 0; q < 4; q++){
      float4 v = *(const float4*)(aRow + k0 + (ca + q) * 4);
      *(float4*)(As + ra * 64 + (((ca + q) ^ (ra & 15)) * 4)) = v;
    }
    #pragma unroll
    for (int q = 0; q < 4; q++){
      int ck = hw * 4 + q;
      float4 u0 = *(const float4*)(wRow + k0 + ck * 8);
      float4 u1 = *(const float4*)(wRow + k0 + ck * 8 + 4);
      ushort4 h0 = make_ushort4(f2bf(u0.x), f2bf(u0.y), f2bf(u0.z), f2bf(u0.w));
      ushort4 h1 = make_ushort4(f2bf(u1.x), f2bf(u1.y), f2bf(u1.z), f2bf(u1.w));
      int cp = ck ^ (rw & 7);
      *(ushort4*)(Ws + rw * 64 + cp * 8) = h0;
      *(ushort4*)(Ws + rw * 64 + cp * 8 + 4) = h1;
    }
    __syncthreads();
    #pragma unroll
    for (int kk = 0; kk < 64; kk += 32){
      bf16x8 af[4], wf[4];
      #pragma unroll
      for (int t = 0; t < 4; t++){
        int r = wm + t * 16 + ml;
        int c0 = (kk >> 2) + quad * 2;
        float4 x0 = *(const float4*)(As + r * 64 + (((c0    ) ^ (r & 15)) * 4));
        float4 x1 = *(const float4*)(As + r * 64 + (((c0 + 1) ^ (r & 15)) * 4));
        af[t] = (bf16x8){ (short)f2bf(x0.x), (short)f2bf(x0.y), (short)f2bf(x0.z), (short)f2bf(x0.w),
                          (short)f2bf(x1.x), (short)f2bf(x1.y), (short)f2bf(x1.z), (short)f2bf(x1.w) };
      }
      #pragma unroll
      for (int t = 0; t < 4; t++){
        int n = wn + t * 16 + ml;
        int c = (kk >> 3) + quad;
        wf[t] = *(const bf16x8*)(Ws + n * 64 + ((c ^ (n & 7)) * 8));
      }
      #pragma unroll
      for (int i = 0; i < 4; i++)
        #pragma unroll
        for (int j = 0; j < 4; j++)
          acc[i][j] = __builtin_amdgcn_mfma_f32_16x16x32_bf16(af[i], wf[j], acc[i][j], 0, 0, 0);
    }
    __syncthreads();
  }
  #pragma unroll
  for (int i = 0; i < 4; i++){
    #pragma unroll
    for (int rr = 0; rr < 4; rr++){
      int row = m0 + wm + i * 16 + quad * 4 + rr;
      if (row < M){
        u16* crow = C + (size_t)row * 256 + wn;
        #pragma unroll
        for (int j = 0; j < 4; j++)
          crow[j * 16 + ml] = f2bf(acc[i][j][rr]);
      }
    }
  }
}

// ---------------- count: per-dst degree + per-edge rank (one atomic per edge)
__global__ __launch_bounds__(256) void count_k(const int* __restrict__ dst,
                                               int* __restrict__ deg,
                                               int* __restrict__ epos){
  int e = blockIdx.x * 256 + threadIdx.x;
  if (e < NE) epos[e] = atomicAdd(&deg[dst[e]], 1);
}

// ---------------- scan degrees -> block-local exclusive offsets + block sums
__global__ __launch_bounds__(256) void scan1_k(const int* __restrict__ deg,
                                               int* __restrict__ offs,
                                               int* __restrict__ bsum){
  __shared__ int lds[256];
  int b = blockIdx.x, tid = threadIdx.x;
  int base = b * 1024 + tid * 4;
  int d[4]; int tsum = 0;
  #pragma unroll
  for (int j = 0; j < 4; j++){
    int node = base + j;
    int v = (node < NND) ? deg[node] : 0;
    d[j] = tsum; tsum += v;
  }
  lds[tid] = tsum; __syncthreads();
  for (int off = 1; off < 256; off <<= 1){
    int v = (tid >= off) ? lds[tid - off] : 0;
    __syncthreads();
    lds[tid] += v;
    __syncthreads();
  }
  int excl = lds[tid] - tsum;
  #pragma unroll
  for (int j = 0; j < 4; j++)
    if (base + j < NND) offs[base + j] = excl + d[j];
  if (tid == 255) bsum[b] = lds[tid];
}

__global__ __launch_bounds__(64) void scan2_k(const int* __restrict__ bsum,
                                              int* __restrict__ bbase, int nb){
  __shared__ int l[64];
  int tid = threadIdx.x;
  int v = (tid < nb) ? bsum[tid] : 0;
  l[tid] = v; __syncthreads();
  for (int off = 1; off < 64; off <<= 1){
    int u = (tid >= off) ? l[tid - off] : 0;
    __syncthreads();
    l[tid] += u;
    __syncthreads();
  }
  bbase[tid] = l[tid] - v;
}

// ---------------- scatter edges into CSR (no atomics)
__global__ __launch_bounds__(256) void scatter_k(const int* __restrict__ dst,
                                                 const int* __restrict__ src,
                                                 const int* __restrict__ ef,
                                                 const int* __restrict__ epos,
                                                 const int* __restrict__ offs,
                                                 const int* __restrict__ bbase,
                                                 int* __restrict__ csr){
  int e = blockIdx.x * 256 + threadIdx.x;
  if (e >= NE) return;
  int d = dst[e];
  int pos = offs[d] + bbase[d >> 10] + epos[e];
  csr[pos] = src[e] | (ef[e] << 16);
}

// ---------------- aggregation, head-sliced for XCD-L2 residency.
// slice h touches fsrc[:, h*32:(h+1)*32] = 3.2 MB -> fits one XCD's 4 MiB L2.
// slice = blockIdx.x & 7 so round-robin dispatch pins slice h to XCD h.
// 16 lanes/node (4 B each = one 64 B line per edge), 4 nodes/wave.
// Also writes rd = 1/sum(w) (the softmax denominator) -> nden_k deleted.
__global__ __launch_bounds__(256) void agg_k(const u16* __restrict__ fsrc,
                                             const int* __restrict__ csr,
                                             const int* __restrict__ offs,
                                             const int* __restrict__ bbase,
                                             const int* __restrict__ deg,
                                             const float* __restrict__ emb,
                                             float* __restrict__ rst,
                                             float* __restrict__ rd){
  const int h = blockIdx.x & 7;
  float m = emb[h];
  #pragma unroll
  for (int t = 1; t < NTY; ++t) m = fmaxf(m, emb[t * 8 + h]);
  const float w0 = __expf(emb[0 * 8 + h] - m);
  const float w1 = __expf(emb[1 * 8 + h] - m);
  const float w2 = __expf(emb[2 * 8 + h] - m);
  const float w3 = __expf(emb[3 * 8 + h] - m);
  const float w4 = __expf(emb[4 * 8 + h] - m);

  const int tid  = threadIdx.x;
  const int node = (blockIdx.x >> 3) * 16 + (tid >> 4);
  const int sl   = tid & 15;
  const u16* base = fsrc + h * 32 + sl * 2;

  const int s = offs[node] + bbase[node >> 10];
  const int e = s + deg[node];
  float a0 = 0.f, a1 = 0.f, ss = 0.f;
  int i = s;
  for (; i + 3 < e; i += 4){
    int p0 = csr[i], p1 = csr[i+1], p2 = csr[i+2], p3 = csr[i+3];
    u32 v0 = *(const u32*)(base + (size_t)(p0 & 0xFFFF) * 256);
    u32 v1 = *(const u32*)(base + (size_t)(p1 & 0xFFFF) * 256);
    u32 v2 = *(const u32*)(base + (size_t)(p2 & 0xFFFF) * 256);
    u32 v3 = *(const u32*)(base + (size_t)(p3 & 0xFFFF) * 256);
    int t0 = ((u32)p0) >> 16, t1 = ((u32)p1) >> 16;
    int t2 = ((u32)p2) >> 16, t3 = ((u32)p3) >> 16;
    float q0 = t0 == 0 ? w0 : t0 == 1 ? w1 : t0 == 2 ? w2 : t0 == 3 ? w3 : w4;
    float q1 = t1 == 0 ? w0 : t1 == 1 ? w1 : t1 == 2 ? w2 : t1 == 3 ? w3 : w4;
    float q2 = t2 == 0 ? w0 : t2 == 1 ? w1 : t2 == 2 ? w2 : t2 == 3 ? w3 : w4;
    float q3 = t3 == 0 ? w0 : t3 == 1 ? w1 : t3 == 2 ? w2 : t3 == 3 ? w3 : w4;
    a0 += q0 * __uint_as_float(v0 << 16);
    a1 += q0 * __uint_as_float(v0 & 0xFFFF0000u);
    a0 += q1 * __uint_as_float(v1 << 16);
    a1 += q1 * __uint_as_float(v1 & 0xFFFF0000u);
    a0 += q2 * __uint_as_float(v2 << 16);
    a1 += q2 * __uint_as_float(v2 & 0xFFFF0000u);
    a0 += q3 * __uint_as_float(v3 << 16);
    a1 += q3 * __uint_as_float(v3 & 0xFFFF0000u);
    ss += (q0 + q1) + (q2 + q3);
  }
  for (; i < e; i++){
    int p0 = csr[i];
    u32 v0 = *(const u32*)(base + (size_t)(p0 & 0xFFFF) * 256);
    int t0 = ((u32)p0) >> 16;
    float q0 = t0 == 0 ? w0 : t0 == 1 ? w1 : t0 == 2 ? w2 : t0 == 3 ? w3 : w4;
    a0 += q0 * __uint_as_float(v0 << 16);
    a1 += q0 * __uint_as_float(v0 & 0xFFFF0000u);
    ss += q0;
  }
  float inv = 1.0f / (ss + 1e-12f);
  *(float2*)(rst + (size_t)node * 256 + h * 32 + sl * 2) = make_float2(a0 * inv, a1 * inv);
  if (sl == 0) rd[(size_t)node * 8 + h] = (ss > 0.f) ? (1.0f / ss) : 0.f;
}

// ---------------- attn output: attn[e,h] = wl[type,h] * rd[dst,h]
__global__ __launch_bounds__(256) void attn_k(const int* __restrict__ dst,
                                              const int* __restrict__ ef,
                                              const float* __restrict__ rd,
                                              const float* __restrict__ emb,
                                              float* __restrict__ attn){
  __shared__ float wl[40];
  int tid = threadIdx.x;
  if (tid < 40){
    int t = tid >> 3, h = tid & 7;
    float m = emb[h];
    for (int tt = 1; tt < NTY; ++tt) m = fmaxf(m, emb[tt * 8 + h]);
    wl[tid] = __expf(emb[t * 8 + h] - m);
  }
  __syncthreads();
  int e = blockIdx.x * 256 + tid;
  if (e >= NE) return;
  int d = dst[e], t = ef[e];
  float4 r0 = *(const float4*)(rd + (size_t)d * 8);
  float4 r1 = *(const float4*)(rd + (size_t)d * 8 + 4);
  const float* wr = wl + t * 8;
  *(float4*)(attn + (size_t)e * 8)     = make_float4(wr[0]*r0.x, wr[1]*r0.y, wr[2]*r0.z, wr[3]*r0.w);
  *(float4*)(attn + (size_t)e * 8 + 4) = make_float4(wr[4]*r1.x, wr[5]*r1.y, wr[6]*r1.z, wr[7]*r1.w);
}

extern "C" void kernel_launch(void* const* d_in, const int* in_sizes, int n_in,
                              void* d_out, int out_size, void* d_ws, size_t ws_size,
                              hipStream_t stream) {
  const float* feat = (const float*)d_in[0];
  const float* fcw  = (const float*)d_in[1];
  const float* emb  = (const float*)d_in[2];
  const int*   ef   = (const int*)d_in[3];
  const int*   src  = (const int*)d_in[4];
  const int*   dst  = (const int*)d_in[5];

  float* rst  = (float*)d_out;                         // [50000, 8, 32]
  float* attn = (float*)d_out + (size_t)NND * NH * ND; // [800000, 8]

  char* ws = (char*)d_ws;
  size_t o = 0;
  u16* fsrc    = (u16*)(ws + o);   o += (size_t)NND * 256 * 2;   // 25.6 MB
  int* csr     = (int*)(ws + o);   o += (size_t)NE * 4;          // 3.2 MB
  int* epos    = (int*)(ws + o);   o += (size_t)NE * 4;          // 3.2 MB
  int* offs    = (int*)(ws + o);   o += 200064;
  int* deg     = (int*)(ws + o);   o += 200064;
  float* rd    = (float*)(ws + o); o += (size_t)NND * NH * 4;    // 1.6 MB
  int* bsum    = (int*)(ws + o);   o += 256;
  int* bbase   = (int*)(ws + o);   o += 256;

  hipMemsetAsync(deg, 0, (size_t)NND * 4, stream);

  gemm_k<<<391, 512, 0, stream>>>(feat, fcw, fsrc, NND);
  count_k<<<(NE + 255) / 256, 256, 0, stream>>>(dst, deg, epos);
  scan1_k<<<(NND + 1023) / 1024, 256, 0, stream>>>(deg, offs, bsum);
  scan2_k<<<1, 64, 0, stream>>>(bsum, bbase, (NND + 1023) / 1024);
  scatter_k<<<(NE + 255) / 256, 256, 0, stream>>>(dst, src, ef, epos, offs, bbase, csr);
  agg_k<<<(NND / 16) * 8, 256, 0, stream>>>(fsrc, csr, offs, bbase, deg, emb, rst, rd);
  attn_k<<<(NE + 255) / 256, 256, 0, stream>>>(dst, ef, rd, emb, attn);
}

// Round 6
// 295.088 us; speedup vs baseline: 1.0986x; 1.0986x over previous
//
#include <hip/hip_runtime.h>

typedef unsigned short u16;
typedef unsigned int u32;
typedef __attribute__((ext_vector_type(8))) short bf16x8;
typedef __attribute__((ext_vector_type(8))) unsigned short u16x8;
typedef __attribute__((ext_vector_type(4))) float f32x4;
typedef __attribute__((ext_vector_type(4))) u32 u32x4;

#define NND 50000
#define NE 800000
#define NH 8
#define ND 32
#define NTY 5

__device__ inline u16 f2bf(float x){
  u32 u = __float_as_uint(x);
  return (u16)((u + 0x7FFFu + ((u >> 16) & 1u)) >> 16);
}

// ---------------- W fp32 -> bf16 (once; 256x256)
__global__ __launch_bounds__(256) void wcvt_k(const float* __restrict__ W,
                                              u16* __restrict__ Wb){
  int i = blockIdx.x * 256 + threadIdx.x;   // 16384 float4s
  f32x4 v = ((const f32x4*)W)[i];
  ((ushort4*)Wb)[i] = make_ushort4(f2bf(v.x), f2bf(v.y), f2bf(v.z), f2bf(v.w));
}

// ---------------- GEMM: feat[M,256] @ Wb[256,256]^T -> fsrc bf16 [M,256]
// 32 m-rows per block (grid 1563 -> ~6 blocks/CU), A staged ONCE for all K
// into 16KB XOR-swizzled LDS; W frags read straight from L2-resident bf16 Wb.
// One __syncthreads total; K-loop is ds_read + coalesced global + MFMA only.
__global__ __launch_bounds__(256, 4) void gemm_k(const float* __restrict__ A,
                                                 const u16* __restrict__ Wb,
                                                 u16* __restrict__ C, int M){
  __shared__ u16 As[32 * 256];   // row r, 16B-chunk c (0..31) at chunk (c ^ (r&7))
  const int tid  = threadIdx.x;
  const int m0   = blockIdx.x * 32;
  const int lane = tid & 63, w = tid >> 6;
  const int wn   = w * 64;
  const int ml   = lane & 15, quad = lane >> 4;

  { // stage A: 8 threads/row, 4 chunks (8 elems) each
    int row = tid >> 3;
    int c0  = (tid & 7) * 4;
    int rag = m0 + row; if (rag >= M) rag = M - 1;
    const float* ar = A + (size_t)rag * 256;
    #pragma unroll
    for (int q = 0; q < 4; q++){
      int c = c0 + q;
      f32x4 x0 = __builtin_nontemporal_load((const f32x4*)(ar + c * 8));
      f32x4 x1 = __builtin_nontemporal_load((const f32x4*)(ar + c * 8 + 4));
      u16x8 h = { f2bf(x0.x), f2bf(x0.y), f2bf(x0.z), f2bf(x0.w),
                  f2bf(x1.x), f2bf(x1.y), f2bf(x1.z), f2bf(x1.w) };
      *(u16x8*)(As + row * 256 + ((c ^ (row & 7)) * 8)) = h;
    }
  }
  __syncthreads();

  f32x4 acc[2][4] = {};
  const u16* wbase = Wb + (size_t)wn * 256;
  #pragma unroll
  for (int ks = 0; ks < 8; ks++){
    bf16x8 af[2], wf[4];
    #pragma unroll
    for (int t = 0; t < 2; t++){
      int r = t * 16 + ml;
      int c = ks * 4 + quad;
      af[t] = *(const bf16x8*)(As + r * 256 + ((c ^ (r & 7)) * 8));
    }
    #pragma unroll
    for (int t = 0; t < 4; t++)
      wf[t] = *(const bf16x8*)(wbase + (size_t)(t * 16 + ml) * 256 + ks * 32 + quad * 8);
    #pragma unroll
    for (int i = 0; i < 2; i++)
      #pragma unroll
      for (int j = 0; j < 4; j++)
        acc[i][j] = __builtin_amdgcn_mfma_f32_16x16x32_bf16(af[i], wf[j], acc[i][j], 0, 0, 0);
  }

  #pragma unroll
  for (int i = 0; i < 2; i++){
    #pragma unroll
    for (int rr = 0; rr < 4; rr++){
      int row = m0 + i * 16 + quad * 4 + rr;
      if (row < M){
        u16* crow = C + (size_t)row * 256 + wn;
        #pragma unroll
        for (int j = 0; j < 4; j++)
          crow[j * 16 + ml] = f2bf(acc[i][j][rr]);
      }
    }
  }
}

// ---------------- count: per-dst degree + per-edge rank (one atomic per edge)
__global__ __launch_bounds__(256) void count_k(const int* __restrict__ dst,
                                               int* __restrict__ deg,
                                               int* __restrict__ epos){
  int e = blockIdx.x * 256 + threadIdx.x;
  if (e < NE){
    int p = atomicAdd(&deg[dst[e]], 1);
    __builtin_nontemporal_store(p, epos + e);
  }
}

// ---------------- scan degrees -> block-local exclusive offsets + block sums
__global__ __launch_bounds__(256) void scan1_k(const int* __restrict__ deg,
                                               int* __restrict__ offs,
                                               int* __restrict__ bsum){
  __shared__ int lds[256];
  int b = blockIdx.x, tid = threadIdx.x;
  int base = b * 1024 + tid * 4;
  int d[4]; int tsum = 0;
  #pragma unroll
  for (int j = 0; j < 4; j++){
    int node = base + j;
    int v = (node < NND) ? deg[node] : 0;
    d[j] = tsum; tsum += v;
  }
  lds[tid] = tsum; __syncthreads();
  for (int off = 1; off < 256; off <<= 1){
    int v = (tid >= off) ? lds[tid - off] : 0;
    __syncthreads();
    lds[tid] += v;
    __syncthreads();
  }
  int excl = lds[tid] - tsum;
  #pragma unroll
  for (int j = 0; j < 4; j++)
    if (base + j < NND) offs[base + j] = excl + d[j];
  if (tid == 255) bsum[b] = lds[tid];
}

__global__ __launch_bounds__(64) void scan2_k(const int* __restrict__ bsum,
                                              int* __restrict__ bbase, int nb){
  __shared__ int l[64];
  int tid = threadIdx.x;
  int v = (tid < nb) ? bsum[tid] : 0;
  l[tid] = v; __syncthreads();
  for (int off = 1; off < 64; off <<= 1){
    int u = (tid >= off) ? l[tid - off] : 0;
    __syncthreads();
    l[tid] += u;
    __syncthreads();
  }
  bbase[tid] = l[tid] - v;
}

// ---------------- scatter edges into CSR (no atomics)
__global__ __launch_bounds__(256) void scatter_k(const int* __restrict__ dst,
                                                 const int* __restrict__ src,
                                                 const int* __restrict__ ef,
                                                 const int* __restrict__ epos,
                                                 const int* __restrict__ offs,
                                                 const int* __restrict__ bbase,
                                                 int* __restrict__ csr){
  int e = blockIdx.x * 256 + threadIdx.x;
  if (e >= NE) return;
  int d = dst[e];
  int pos = offs[d] + bbase[d >> 10] + epos[e];
  csr[pos] = src[e] | (ef[e] << 16);
}

// ---------------- aggregation (round-3 structure): 2 nodes/wave, 512B/edge,
// unroll x4. Also writes rd = 1/sum(w) (softmax denominator) for attn_k.
// rst stores + csr loads nontemporal so 50MB streaming doesn't evict fsrc L2.
__device__ inline void acc8(u32x4 v, float wt, float* a){
  a[0] += wt * __uint_as_float(v.x << 16);
  a[1] += wt * __uint_as_float(v.x & 0xFFFF0000u);
  a[2] += wt * __uint_as_float(v.y << 16);
  a[3] += wt * __uint_as_float(v.y & 0xFFFF0000u);
  a[4] += wt * __uint_as_float(v.z << 16);
  a[5] += wt * __uint_as_float(v.z & 0xFFFF0000u);
  a[6] += wt * __uint_as_float(v.w << 16);
  a[7] += wt * __uint_as_float(v.w & 0xFFFF0000u);
}

__global__ __launch_bounds__(256) void agg_k(const u16* __restrict__ fsrc,
                                             const int* __restrict__ csr,
                                             const int* __restrict__ offs,
                                             const int* __restrict__ bbase,
                                             const int* __restrict__ deg,
                                             const float* __restrict__ emb,
                                             float* __restrict__ rst,
                                             float* __restrict__ rd){
  __shared__ float wl[40];
  int tid = threadIdx.x;
  if (tid < 40){
    int t = tid >> 3, h = tid & 7;
    float m = emb[h];
    for (int tt = 1; tt < NTY; ++tt) m = fmaxf(m, emb[tt * 8 + h]);
    wl[tid] = __expf(emb[t * 8 + h] - m);
  }
  __syncthreads();
  int node = blockIdx.x * 8 + (tid >> 5);
  int sl = tid & 31;
  int c = sl * 8;
  int h = sl >> 2;
  int s = offs[node] + bbase[node >> 10];
  int e = s + deg[node];
  float a[8] = {0,0,0,0,0,0,0,0};
  float ss = 0.f;
  int i = s;
  for (; i + 3 < e; i += 4){
    int p0 = __builtin_nontemporal_load(csr + i);
    int p1 = __builtin_nontemporal_load(csr + i + 1);
    int p2 = __builtin_nontemporal_load(csr + i + 2);
    int p3 = __builtin_nontemporal_load(csr + i + 3);
    u32x4 v0 = *(const u32x4*)(fsrc + (size_t)(p0 & 0xFFFF) * 256 + c);
    u32x4 v1 = *(const u32x4*)(fsrc + (size_t)(p1 & 0xFFFF) * 256 + c);
    u32x4 v2 = *(const u32x4*)(fsrc + (size_t)(p2 & 0xFFFF) * 256 + c);
    u32x4 v3 = *(const u32x4*)(fsrc + (size_t)(p3 & 0xFFFF) * 256 + c);
    float w0 = wl[(((u32)p0) >> 16) * 8 + h];
    float w1 = wl[(((u32)p1) >> 16) * 8 + h];
    float w2 = wl[(((u32)p2) >> 16) * 8 + h];
    float w3 = wl[(((u32)p3) >> 16) * 8 + h];
    acc8(v0, w0, a); acc8(v1, w1, a); acc8(v2, w2, a); acc8(v3, w3, a);
    ss += (w0 + w1) + (w2 + w3);
  }
  for (; i < e; i++){
    int p0 = __builtin_nontemporal_load(csr + i);
    u32x4 v0 = *(const u32x4*)(fsrc + (size_t)(p0 & 0xFFFF) * 256 + c);
    float w0 = wl[(((u32)p0) >> 16) * 8 + h];
    acc8(v0, w0, a);
    ss += w0;
  }
  float inv = 1.0f / (ss + 1e-12f);
  float* orow = rst + (size_t)node * 256 + c;
  f32x4 o0 = { a[0]*inv, a[1]*inv, a[2]*inv, a[3]*inv };
  f32x4 o1 = { a[4]*inv, a[5]*inv, a[6]*inv, a[7]*inv };
  __builtin_nontemporal_store(o0, (f32x4*)orow);
  __builtin_nontemporal_store(o1, (f32x4*)(orow + 4));
  if ((sl & 3) == 0)
    rd[(size_t)node * 8 + h] = (ss > 0.f) ? (1.0f / ss) : 0.f;
}

// ---------------- attn output: attn[e,h] = wl[type,h] * rd[dst,h]
__global__ __launch_bounds__(256) void attn_k(const int* __restrict__ dst,
                                              const int* __restrict__ ef,
                                              const float* __restrict__ rd,
                                              const float* __restrict__ emb,
                                              float* __restrict__ attn){
  __shared__ float wl[40];
  int tid = threadIdx.x;
  if (tid < 40){
    int t = tid >> 3, h = tid & 7;
    float m = emb[h];
    for (int tt = 1; tt < NTY; ++tt) m = fmaxf(m, emb[tt * 8 + h]);
    wl[tid] = __expf(emb[t * 8 + h] - m);
  }
  __syncthreads();
  int e = blockIdx.x * 256 + tid;
  if (e >= NE) return;
  int d = dst[e], t = ef[e];
  f32x4 r0 = *(const f32x4*)(rd + (size_t)d * 8);
  f32x4 r1 = *(const f32x4*)(rd + (size_t)d * 8 + 4);
  const float* wr = wl + t * 8;
  f32x4 o0 = { wr[0]*r0.x, wr[1]*r0.y, wr[2]*r0.z, wr[3]*r0.w };
  f32x4 o1 = { wr[4]*r1.x, wr[5]*r1.y, wr[6]*r1.z, wr[7]*r1.w };
  __builtin_nontemporal_store(o0, (f32x4*)(attn + (size_t)e * 8));
  __builtin_nontemporal_store(o1, (f32x4*)(attn + (size_t)e * 8 + 4));
}

extern "C" void kernel_launch(void* const* d_in, const int* in_sizes, int n_in,
                              void* d_out, int out_size, void* d_ws, size_t ws_size,
                              hipStream_t stream) {
  const float* feat = (const float*)d_in[0];
  const float* fcw  = (const float*)d_in[1];
  const float* emb  = (const float*)d_in[2];
  const int*   ef   = (const int*)d_in[3];
  const int*   src  = (const int*)d_in[4];
  const int*   dst  = (const int*)d_in[5];

  float* rst  = (float*)d_out;                         // [50000, 8, 32]
  float* attn = (float*)d_out + (size_t)NND * NH * ND; // [800000, 8]

  char* ws = (char*)d_ws;
  size_t o = 0;
  u16* fsrc    = (u16*)(ws + o);   o += (size_t)NND * 256 * 2;   // 25.6 MB
  int* csr     = (int*)(ws + o);   o += (size_t)NE * 4;          // 3.2 MB
  int* epos    = (int*)(ws + o);   o += (size_t)NE * 4;          // 3.2 MB
  int* offs    = (int*)(ws + o);   o += 200064;
  int* deg     = (int*)(ws + o);   o += 200064;
  float* rd    = (float*)(ws + o); o += (size_t)NND * NH * 4;    // 1.6 MB
  u16* Wb      = (u16*)(ws + o);   o += (size_t)256 * 256 * 2;   // 128 KB
  int* bsum    = (int*)(ws + o);   o += 256;
  int* bbase   = (int*)(ws + o);   o += 256;

  (void)hipMemsetAsync(deg, 0, (size_t)NND * 4, stream);

  wcvt_k<<<64, 256, 0, stream>>>(fcw, Wb);
  gemm_k<<<(NND + 31) / 32, 256, 0, stream>>>(feat, Wb, fsrc, NND);
  count_k<<<(NE + 255) / 256, 256, 0, stream>>>(dst, deg, epos);
  scan1_k<<<(NND + 1023) / 1024, 256, 0, stream>>>(deg, offs, bsum);
  scan2_k<<<1, 64, 0, stream>>>(bsum, bbase, (NND + 1023) / 1024);
  scatter_k<<<(NE + 255) / 256, 256, 0, stream>>>(dst, src, ef, epos, offs, bbase, csr);
  agg_k<<<NND / 8, 256, 0, stream>>>(fsrc, csr, offs, bbase, deg, emb, rst, rd);
  attn_k<<<(NE + 255) / 256, 256, 0, stream>>>(dst, ef, rd, emb, attn);
}